// Round 13
// baseline (239.645 us; speedup 1.0000x reference)
//
#include <hip/hip_runtime.h>
#include <hip/hip_bf16.h>
#include <stdint.h>

typedef __bf16 bf16;
typedef __bf16 bf16x8 __attribute__((ext_vector_type(8)));
typedef float  f32x2  __attribute__((ext_vector_type(2)));
typedef float  f32x4  __attribute__((ext_vector_type(4)));
typedef float  f32x16 __attribute__((ext_vector_type(16)));

#define D_MODEL 2048
#define KV_DIM  512
#define SEQ     2048
#define BATCH   2
#define MTOT    (BATCH*SEQ)            // 4096
#define QKV_N   3072                   // 2048 Q + 512 K + 512 V
#define QSCALE  (0.125f*1.44269504088896f)  // 1/sqrt(64) * log2(e)

#if __has_builtin(__builtin_amdgcn_exp2f)
#define EXP2(x) __builtin_amdgcn_exp2f(x)
#else
#define EXP2(x) exp2f(x)
#endif

// ---------------- f32 -> bf16 convert (vectorized x4) ----------------
__global__ __launch_bounds__(256) void cvt_f32_bf16(const float* __restrict__ in,
                                                    bf16* __restrict__ out, int n) {
  int i = (blockIdx.x * 256 + threadIdx.x) * 4;
  if (i < n) {
    float4 v = *reinterpret_cast<const float4*>(in + i);
    bf16 o[4] = {(bf16)v.x, (bf16)v.y, (bf16)v.z, (bf16)v.w};
    *reinterpret_cast<uint64_t*>(out + i) = *reinterpret_cast<const uint64_t*>(o);
  }
}

// ------------- all 4 weight transposes in one launch (z selects matrix) -------------
__global__ __launch_bounds__(256) void transpose_all(
    const float* __restrict__ Wq, const float* __restrict__ Wk,
    const float* __restrict__ Wv, const float* __restrict__ Wo,
    bf16* __restrict__ Wall, bf16* __restrict__ Wot) {
  const int z = blockIdx.z;
  const float* W; bf16* dst; int N;
  if (z == 0)      { W = Wq; dst = Wall;                          N = 2048; }
  else if (z == 1) { W = Wk; dst = Wall + (size_t)2048 * 2048;    N = 512;  }
  else if (z == 2) { W = Wv; dst = Wall + (size_t)2560 * 2048;    N = 512;  }
  else             { W = Wo; dst = Wot;                           N = 2048; }
  const int n0 = blockIdx.x * 64, k0 = blockIdx.y * 64;
  if (n0 >= N) return;
  __shared__ float tile[64][65];
  const int tx = threadIdx.x & 63;
  const int ty = threadIdx.x >> 6;   // 0..3
  #pragma unroll
  for (int i = ty; i < 64; i += 4)
    tile[i][tx] = W[(size_t)(k0 + i) * N + n0 + tx];
  __syncthreads();
  #pragma unroll
  for (int i = ty; i < 64; i += 4)
    dst[(size_t)(n0 + i) * 2048 + k0 + tx] = (bf16)tile[tx][i];
}

// ------------- transpose V: QKV[token][2560..3071] -> Vtg[(b*8+kvh)*64+d][S] -------------
__global__ __launch_bounds__(256) void transpose_v(const bf16* __restrict__ QKV,
                                                   bf16* __restrict__ Vtg) {
  __shared__ bf16 t[64][72];
  const int st = blockIdx.x;        // s-tile 0..31
  const int bk = blockIdx.y;        // 0..15 = b*8+kvh
  const int b = bk >> 3, kvh = bk & 7;
  const int tid = threadIdx.x;
  const int r = tid >> 2, c = (tid & 3) * 16;
  const bf16* src = QKV + (size_t)(b * SEQ + st * 64 + r) * QKV_N + 2560 + kvh * 64 + c;
  *(bf16x8*)&t[r][c]     = *(const bf16x8*)src;
  *(bf16x8*)&t[r][c + 8] = *(const bf16x8*)(src + 8);
  __syncthreads();
  bf16 tmp[16];
  #pragma unroll
  for (int j = 0; j < 16; ++j) tmp[j] = t[c + j][r];
  bf16* dst = Vtg + (size_t)(bk * 64 + r) * SEQ + st * 64 + c;
  *(bf16x8*)dst       = *(const bf16x8*)tmp;
  *(bf16x8*)(dst + 8) = *(const bf16x8*)(tmp + 8);
}

// ---------------- async global->LDS, 16B per lane ----------------
__device__ __forceinline__ void gload_lds16(const bf16* g, bf16* l) {
  __builtin_amdgcn_global_load_lds(
      (const __attribute__((address_space(1))) uint32_t*)g,
      (__attribute__((address_space(3))) uint32_t*)l, 16, 0, 0);
}

__device__ __forceinline__ uint32_t pk2(float a, float b) {
  union { bf16 h[2]; uint32_t u; } v;
  v.h[0] = (bf16)a; v.h[1] = (bf16)b;
  return v.u;
}

// ---------------- deep-pipelined GEMM: C[4096][N] = A @ Bt^T + bias ----------------
// BM=256, BN=NF*64; grid 16x16 = 256 blocks (1/CU).
// R13: 4 waves (2M x 2N), per-wave 128 x NF*32 -> 4m x NFn 32x32 tiles/wave.
// Cuts LDS reads/K-tile 160->112 KB (NF3): below the 1536-cyc matrix floor.
// 12 independent accumulators saturate the matrix pipe from 1 wave/SIMD.
// acc = 192 VGPR -> __launch_bounds__(256,1) = 512-reg budget (no-spill by design).
// Sync skeleton / swizzle / counted-vmcnt identical to R12 (proven).
template<int NF, int OUT_BF16>
__global__ __launch_bounds__(256, 1) void gemm256(
    const bf16* __restrict__ A, const bf16* __restrict__ Bt,
    const float* __restrict__ b0, const float* __restrict__ b1,
    const float* __restrict__ b2, int sp1, int sp2, int nscale, float scale,
    void* __restrict__ Cout, int N, int K)
{
  __shared__ bf16 As[2][256 * 64];
  __shared__ bf16 Bs[2][NF * 64 * 64];

  const int tid = threadIdx.x, lane = tid & 63;
  const int wid = tid >> 6;                  // 0..3
  const int wr = wid >> 1, wc = wid & 1;     // 2M x 2N wave grid
  const int l31 = lane & 31, hi2 = lane >> 5;
  const int rx = l31 & 7;

  // XCD-chunked swizzle over the fixed 16x16 grid
  const int bid = blockIdx.y * 16 + blockIdx.x;
  const int swz = (bid & 7) * 32 + (bid >> 3);
  const int m0 = (swz >> 4) * 256, n0 = (swz & 15) * (NF * 64);

  // staging map: 256 threads x 16B = 4 KB per load row-group (32 rows)
  // A: 8 loads (256 rows), B: 2*NF loads (NF*64 rows)
  const int srow = tid >> 3;                 // 0..31
  const int schk = (tid & 7) ^ (srow & 7);   // pre-swizzled source chunk
  const bf16* aSrc = A  + (size_t)(m0 + srow) * K + schk * 8;
  const bf16* bSrc = Bt + (size_t)(n0 + srow) * K + schk * 8;
  const size_t rstep = (size_t)32 * K;

  f32x16 acc[4][NF] = {};                    // [m-tile][n-tile], 32x32 each

  const int NT = K / 64;                     // 32

#define G256_STAGE(T, BUF)                                            \
  {                                                                   \
    const bf16* a_ = aSrc + (T) * 64;                                 \
    _Pragma("unroll")                                                 \
    for (int j = 0; j < 8; ++j)                                       \
      gload_lds16(a_ + j * rstep, &As[BUF][j * 2048 + tid * 8]);      \
    const bf16* b_ = bSrc + (T) * 64;                                 \
    _Pragma("unroll")                                                 \
    for (int j = 0; j < 2 * NF; ++j)                                  \
      gload_lds16(b_ + j * rstep, &Bs[BUF][j * 2048 + tid * 8]);      \
  }

#define G256_WAITL()                                                  \
  if constexpr (NF == 3) asm volatile("s_waitcnt vmcnt(14)" ::: "memory"); \
  else                   asm volatile("s_waitcnt vmcnt(12)" ::: "memory");

#define G256_BODY(BUF)                                                \
  {                                                                   \
    _Pragma("unroll")                                                 \
    for (int ks = 0; ks < 4; ++ks) {                                  \
      bf16x8 af[4], bfv[NF];                                          \
      _Pragma("unroll")                                               \
      for (int m = 0; m < 4; ++m)                                     \
        af[m] = *(const bf16x8*)&As[BUF][(wr * 128 + m * 32 + l31) * 64 \
                                         + (((ks * 2 + hi2) ^ rx) * 8)]; \
      _Pragma("unroll")                                               \
      for (int n = 0; n < NF; ++n)                                    \
        bfv[n] = *(const bf16x8*)&Bs[BUF][(wc * (NF * 32) + n * 32 + l31) * 64 \
                                          + (((ks * 2 + hi2) ^ rx) * 8)]; \
      __builtin_amdgcn_s_setprio(1);                                  \
      _Pragma("unroll")                                               \
      for (int m = 0; m < 4; ++m)                                     \
        _Pragma("unroll")                                             \
        for (int n = 0; n < NF; ++n)                                  \
          acc[m][n] = __builtin_amdgcn_mfma_f32_32x32x16_bf16(        \
              af[m], bfv[n], acc[m][n], 0, 0, 0);                     \
      __builtin_amdgcn_s_setprio(0);                                  \
    }                                                                 \
  }

  // prologue: stage tiles 0,1; wait tile 0; sync
  G256_STAGE(0, 0)
  G256_STAGE(1, 1)
  G256_WAITL()
  __builtin_amdgcn_sched_barrier(0);
  __builtin_amdgcn_s_barrier();
  __builtin_amdgcn_sched_barrier(0);

  for (int t = 0; t < NT; t += 2) {
    #pragma unroll
    for (int u = 0; u < 2; ++u) {            // tile tt = t+u lives in buf u
      G256_BODY(u)
      __builtin_amdgcn_sched_barrier(0);
      __builtin_amdgcn_s_barrier();          // all waves done reading buf u
      __builtin_amdgcn_sched_barrier(0);
      const int tt = t + u;
      if (tt < NT - 2) {
        G256_STAGE(tt + 2, u)                // overwrite buf u with tile tt+2
        G256_WAITL()                         // tile tt+1's loads now complete
      } else {
        asm volatile("s_waitcnt vmcnt(0)" ::: "memory");
      }
      __builtin_amdgcn_sched_barrier(0);
      __builtin_amdgcn_s_barrier();          // tile tt+1 visible block-wide
      __builtin_amdgcn_sched_barrier(0);
    }
  }

#undef G256_STAGE
#undef G256_WAITL
#undef G256_BODY

  // epilogue: bias + scale + store (32x32 C/D layout: col=lane&31,
  // row=(r&3)+8*(r>>2)+4*hi2 — m101-verified)
  const int cb = n0 + wc * (NF * 32) + l31;
  #pragma unroll
  for (int n = 0; n < NF; ++n) {
    const int col = cb + n * 32;
    float bv;
    if (col < sp1)      bv = b0[col];
    else if (col < sp2) bv = b1[col - sp1];
    else                bv = b2[col - sp2];
    const float scl = (col < nscale) ? scale : 1.0f;
    #pragma unroll
    for (int m = 0; m < 4; ++m) {
      const int rb = m0 + wr * 128 + m * 32 + 4 * hi2;
      #pragma unroll
      for (int r = 0; r < 16; ++r) {
        const int row = rb + (r & 3) + 8 * (r >> 2);
        const float v = (acc[m][n][r] + bv) * scl;
        if (OUT_BF16) ((bf16*)Cout)[(size_t)row * N + col] = (bf16)v;
        else          ((float*)Cout)[(size_t)row * N + col] = v;
      }
    }
  }
}

// ---------------- flash attention (EXACT R5/R10/R11/R12 kernel — frozen) ----------------
__global__ __launch_bounds__(256) void attn_kernel(
    const bf16* __restrict__ QKV, const bf16* __restrict__ Vtg, bf16* __restrict__ ctx)
{
  __shared__ bf16 smem[4][64 * 64];   // [0..1] K dbuf, [2..3] Vt dbuf; 32 KB

  const int tid = threadIdx.x, lane = tid & 63, wid = tid >> 6;
  const int l31 = lane & 31, hi = lane >> 5;
  const int qt = blockIdx.x & 15;
  const int bh = blockIdx.x >> 4;
  const int h = bh & 31, b = bh >> 5, kvh = h >> 2;

  const bf16* gK = QKV + (size_t)b * SEQ * QKV_N + 2048 + kvh * 64;
  const bf16* gV = Vtg + (size_t)(b * 8 + kvh) * 64 * SEQ;

  const int sr  = lane >> 3;            // staging row within 8-row group
  const int scn = (lane & 7) ^ sr;      // pre-swizzled logical chunk

  bf16x8 qf[4];
  {
    const bf16* qp = QKV + (size_t)(b * SEQ + qt * 128 + wid * 32 + l31) * QKV_N + h * 64 + hi * 8;
    #pragma unroll
    for (int kt = 0; kt < 4; ++kt) qf[kt] = *(const bf16x8*)(qp + kt * 16);
  }

  bf16x8 onesv;
  #pragma unroll
  for (int j = 0; j < 8; ++j) onesv[j] = (bf16)1.0f;

  f32x16 o0 = {}, o1 = {};
  f32x16 lacc = {};

  const int row0 = (wid * 2 + 0) * 8 + sr;
  const int row1 = (wid * 2 + 1) * 8 + sr;
  const bf16* pK0 = gK + (size_t)row0 * QKV_N + scn * 8;
  const bf16* pK1 = gK + (size_t)row1 * QKV_N + scn * 8;
  const bf16* pV0 = gV + (size_t)row0 * SEQ + scn * 8;
  const bf16* pV1 = gV + (size_t)row1 * SEQ + scn * 8;

  gload_lds16(pK0, &smem[0][(wid * 2 + 0) * 512]);
  gload_lds16(pK1, &smem[0][(wid * 2 + 1) * 512]);
  gload_lds16(pV0, &smem[2][(wid * 2 + 0) * 512]);
  gload_lds16(pV1, &smem[2][(wid * 2 + 1) * 512]);
  pK0 += (size_t)64 * QKV_N; pK1 += (size_t)64 * QKV_N; pV0 += 64; pV1 += 64;
  __syncthreads();

  const int rx = l31 & 7;

  for (int it = 0; it < 32; ++it) {
    const int cur = it & 1;
    if (it < 31) {
      gload_lds16(pK0, &smem[cur ^ 1][(wid * 2 + 0) * 512]);
      gload_lds16(pK1, &smem[cur ^ 1][(wid * 2 + 1) * 512]);
      gload_lds16(pV0, &smem[2 + (cur ^ 1)][(wid * 2 + 0) * 512]);
      gload_lds16(pV1, &smem[2 + (cur ^ 1)][(wid * 2 + 1) * 512]);
      pK0 += (size_t)64 * QKV_N; pK1 += (size_t)64 * QKV_N; pV0 += 64; pV1 += 64;
    }
    const bf16* Kb = smem[cur];
    const bf16* Vb = smem[2 + cur];

    bf16x8 kf[8];
    #pragma unroll
    for (int kt = 0; kt < 4; ++kt) {
      const int ck = hi + 2 * kt;
      kf[kt]     = *(const bf16x8*)(Kb + (size_t)l31 * 64        + ((ck ^ rx) * 8));
      kf[kt + 4] = *(const bf16x8*)(Kb + (size_t)(32 + l31) * 64 + ((ck ^ rx) * 8));
    }
    f32x16 s0v = {}, s1v = {};
    __builtin_amdgcn_s_setprio(1);
    #pragma unroll
    for (int kt = 0; kt < 4; ++kt) {
      s0v = __builtin_amdgcn_mfma_f32_32x32x16_bf16(kf[kt],     qf[kt], s0v, 0, 0, 0);
      s1v = __builtin_amdgcn_mfma_f32_32x32x16_bf16(kf[kt + 4], qf[kt], s1v, 0, 0, 0);
    }
    __builtin_amdgcn_s_setprio(0);

    bf16x8 vf[8];
    #pragma unroll
    for (int s = 0; s < 4; ++s) {
      const int ck = hi + 2 * s;
      vf[s]     = *(const bf16x8*)(Vb + (size_t)l31 * 64        + ((ck ^ rx) * 8));
      vf[s + 4] = *(const bf16x8*)(Vb + (size_t)(32 + l31) * 64 + ((ck ^ rx) * 8));
    }

    #pragma unroll
    for (int r = 0; r < 16; ++r) { s0v[r] = EXP2(s0v[r]); s1v[r] = EXP2(s1v[r]); }

    #pragma unroll
    for (int s = 0; s < 4; ++s) {
      const f32x16& sv = (s < 2) ? s0v : s1v;
      const int rb = (s & 1) * 8;
      uint32_t Aw = pk2(sv[rb + 0], sv[rb + 1]);
      uint32_t Bw = pk2(sv[rb + 2], sv[rb + 3]);
      uint32_t Cw = pk2(sv[rb + 4], sv[rb + 5]);
      uint32_t Dw = pk2(sv[rb + 6], sv[rb + 7]);
      union { uint32_t w[4]; bf16x8 v; } pf;
#if __has_builtin(__builtin_amdgcn_permlane32_swap)
      auto rA = __builtin_amdgcn_permlane32_swap(Aw, Cw, false, false);
      auto rB = __builtin_amdgcn_permlane32_swap(Bw, Dw, false, false);
      pf.w[0] = rA[0]; pf.w[1] = rB[0]; pf.w[2] = rA[1]; pf.w[3] = rB[1];
#else
      uint32_t U = hi ? Aw : Cw;
      uint32_t W = hi ? Bw : Dw;
      uint32_t pU = (uint32_t)__shfl_xor((int)U, 32);
      uint32_t pW = (uint32_t)__shfl_xor((int)W, 32);
      pf.w[0] = hi ? pU : Aw;
      pf.w[1] = hi ? pW : Bw;
      pf.w[2] = hi ? Cw : pU;
      pf.w[3] = hi ? Dw : pW;
#endif
      __builtin_amdgcn_s_setprio(1);
      o0 = __builtin_amdgcn_mfma_f32_32x32x16_bf16(vf[s],     pf.v, o0, 0, 0, 0);
      o1 = __builtin_amdgcn_mfma_f32_32x32x16_bf16(vf[s + 4], pf.v, o1, 0, 0, 0);
      lacc = __builtin_amdgcn_mfma_f32_32x32x16_bf16(onesv,   pf.v, lacc, 0, 0, 0);
      __builtin_amdgcn_s_setprio(0);
    }
    __syncthreads();
  }

  const float inv = 1.0f / lacc[0];
  o0 *= inv; o1 *= inv;

  uint32_t* ot = (uint32_t*)((bf16*)smem + wid * 2304);
  #pragma unroll
  for (int r = 0; r < 16; r += 2) {
    const int d = (r & 3) + 8 * (r >> 2) + 4 * hi;
    ot[l31 * 36 + (d >> 1)]        = pk2(o0[r], o0[r + 1]);
    ot[l31 * 36 + ((32 + d) >> 1)] = pk2(o1[r], o1[r + 1]);
  }
  __syncthreads();
  {
    const int q2 = lane >> 1, hf = lane & 1;
    const bf16* src = (const bf16*)smem + wid * 2304 + q2 * 72 + hf * 32;
    bf16* dst = ctx + (size_t)(b * SEQ + qt * 128 + wid * 32 + q2) * D_MODEL + h * 64 + hf * 32;
    #pragma unroll
    for (int k = 0; k < 4; ++k)
      *(bf16x8*)(dst + k * 8) = *(const bf16x8*)(src + k * 8);
  }
}

// ---------------------------------------------------------------------------
extern "C" void kernel_launch(void* const* d_in, const int* in_sizes, int n_in,
                              void* d_out, int out_size, void* d_ws, size_t ws_size,
                              hipStream_t stream) {
  const float* x  = (const float*)d_in[0];
  const float* Wq = (const float*)d_in[1];
  const float* bq = (const float*)d_in[2];
  const float* Wk = (const float*)d_in[3];
  const float* bk = (const float*)d_in[4];
  const float* Wv = (const float*)d_in[5];
  const float* bv = (const float*)d_in[6];
  const float* Wo = (const float*)d_in[7];
  const float* bo = (const float*)d_in[8];
  float* out = (float*)d_out;

  char* ws = (char*)d_ws;
  size_t off = 0;
  bf16* xb   = (bf16*)(ws + off); off += (size_t)MTOT * D_MODEL * 2;       // x bf16
  bf16* Wall = (bf16*)(ws + off); off += (size_t)QKV_N * D_MODEL * 2;      // [Wq^T;Wk^T;Wv^T]
  bf16* Wot  = (bf16*)(ws + off); off += (size_t)D_MODEL * D_MODEL * 2;    // Wo^T
  bf16* QKV  = (bf16*)(ws + off); off += (size_t)MTOT * QKV_N * 2;         // [Q|K|V]
  bf16* ctx  = (bf16*)(ws + off); off += (size_t)MTOT * D_MODEL * 2;       // attn out
  bf16* Vtg  = (bf16*)(ws + off); off += (size_t)16 * 64 * SEQ * 2;        // V^T

  // 1) x -> bf16
  {
    int n = MTOT * D_MODEL;
    cvt_f32_bf16<<<n / 4 / 256, 256, 0, stream>>>(x, xb, n);
  }
  // 2) all weight transposes, one launch
  transpose_all<<<dim3(32, 32, 4), 256, 0, stream>>>(Wq, Wk, Wv, Wo, Wall, Wot);

  // 3) fused QKV projection: BM=256 x BN=192 -> 16x16 = 256 blocks (full fill)
  gemm256<3, 1><<<dim3(16, 16), 256, 0, stream>>>(
      xb, Wall, bq, bk, bv, 2048, 2560, 2048, QSCALE, QKV, QKV_N, D_MODEL);

  // 3b) V -> V^T
  transpose_v<<<dim3(SEQ / 64, 16), 256, 0, stream>>>(QKV, Vtg);

  // 4) attention
  attn_kernel<<<dim3((SEQ / 128) * BATCH * 32), 256, 0, stream>>>(QKV, Vtg, ctx);

  // 5) output projection: BM=256 x BN=128 -> 16x16 = 256 blocks (full fill)
  gemm256<2, 0><<<dim3(16, 16), 256, 0, stream>>>(
      ctx, Wot, bo, bo, bo, 2048, 2048, 0, 1.0f, out, D_MODEL, D_MODEL);
}

// Round 14
// 235.230 us; speedup vs baseline: 1.0188x; 1.0188x over previous
//
#include <hip/hip_runtime.h>
#include <hip/hip_bf16.h>
#include <stdint.h>

typedef __bf16 bf16;
typedef __bf16 bf16x8 __attribute__((ext_vector_type(8)));
typedef float  f32x2  __attribute__((ext_vector_type(2)));
typedef float  f32x4  __attribute__((ext_vector_type(4)));
typedef float  f32x16 __attribute__((ext_vector_type(16)));

#define D_MODEL 2048
#define KV_DIM  512
#define SEQ     2048
#define BATCH   2
#define MTOT    (BATCH*SEQ)            // 4096
#define QKV_N   3072                   // 2048 Q + 512 K + 512 V
#define QSCALE  (0.125f*1.44269504088896f)  // 1/sqrt(64) * log2(e)

#if __has_builtin(__builtin_amdgcn_exp2f)
#define EXP2(x) __builtin_amdgcn_exp2f(x)
#else
#define EXP2(x) exp2f(x)
#endif

// ---------------- f32 -> bf16 convert (vectorized x4) ----------------
__global__ __launch_bounds__(256) void cvt_f32_bf16(const float* __restrict__ in,
                                                    bf16* __restrict__ out, int n) {
  int i = (blockIdx.x * 256 + threadIdx.x) * 4;
  if (i < n) {
    float4 v = *reinterpret_cast<const float4*>(in + i);
    bf16 o[4] = {(bf16)v.x, (bf16)v.y, (bf16)v.z, (bf16)v.w};
    *reinterpret_cast<uint64_t*>(out + i) = *reinterpret_cast<const uint64_t*>(o);
  }
}

// ------------- all 4 weight transposes in one launch (z selects matrix) -------------
__global__ __launch_bounds__(256) void transpose_all(
    const float* __restrict__ Wq, const float* __restrict__ Wk,
    const float* __restrict__ Wv, const float* __restrict__ Wo,
    bf16* __restrict__ Wall, bf16* __restrict__ Wot) {
  const int z = blockIdx.z;
  const float* W; bf16* dst; int N;
  if (z == 0)      { W = Wq; dst = Wall;                          N = 2048; }
  else if (z == 1) { W = Wk; dst = Wall + (size_t)2048 * 2048;    N = 512;  }
  else if (z == 2) { W = Wv; dst = Wall + (size_t)2560 * 2048;    N = 512;  }
  else             { W = Wo; dst = Wot;                           N = 2048; }
  const int n0 = blockIdx.x * 64, k0 = blockIdx.y * 64;
  if (n0 >= N) return;
  __shared__ float tile[64][65];
  const int tx = threadIdx.x & 63;
  const int ty = threadIdx.x >> 6;   // 0..3
  #pragma unroll
  for (int i = ty; i < 64; i += 4)
    tile[i][tx] = W[(size_t)(k0 + i) * N + n0 + tx];
  __syncthreads();
  #pragma unroll
  for (int i = ty; i < 64; i += 4)
    dst[(size_t)(n0 + i) * 2048 + k0 + tx] = (bf16)tile[tx][i];
}

// ------------- transpose V: QKV[token][2560..3071] -> Vtg[(b*8+kvh)*64+d][S] -------------
__global__ __launch_bounds__(256) void transpose_v(const bf16* __restrict__ QKV,
                                                   bf16* __restrict__ Vtg) {
  __shared__ bf16 t[64][72];
  const int st = blockIdx.x;        // s-tile 0..31
  const int bk = blockIdx.y;        // 0..15 = b*8+kvh
  const int b = bk >> 3, kvh = bk & 7;
  const int tid = threadIdx.x;
  const int r = tid >> 2, c = (tid & 3) * 16;
  const bf16* src = QKV + (size_t)(b * SEQ + st * 64 + r) * QKV_N + 2560 + kvh * 64 + c;
  *(bf16x8*)&t[r][c]     = *(const bf16x8*)src;
  *(bf16x8*)&t[r][c + 8] = *(const bf16x8*)(src + 8);
  __syncthreads();
  bf16 tmp[16];
  #pragma unroll
  for (int j = 0; j < 16; ++j) tmp[j] = t[c + j][r];
  bf16* dst = Vtg + (size_t)(bk * 64 + r) * SEQ + st * 64 + c;
  *(bf16x8*)dst       = *(const bf16x8*)tmp;
  *(bf16x8*)(dst + 8) = *(const bf16x8*)(tmp + 8);
}

// ---------------- async global->LDS, 16B per lane ----------------
__device__ __forceinline__ void gload_lds16(const bf16* g, bf16* l) {
  __builtin_amdgcn_global_load_lds(
      (const __attribute__((address_space(1))) uint32_t*)g,
      (__attribute__((address_space(3))) uint32_t*)l, 16, 0, 0);
}

__device__ __forceinline__ uint32_t pk2(float a, float b) {
  union { bf16 h[2]; uint32_t u; } v;
  v.h[0] = (bf16)a; v.h[1] = (bf16)b;
  return v.u;
}

// ---------------- deep-pipelined GEMM: C[4096][N] = A @ Bt^T + bias ----------------
// R12-exact (best measured): BM=256, BN=NF*64; grid 16x16 = 256 blocks.
// 8 waves as 4M x 2N; per-wave 64 rows x NF*32 cols. mfma_f32_32x32x16.
// __launch_bounds__(512,2); counted-vmcnt 2-tile pipeline.
template<int NF, int OUT_BF16>
__global__ __launch_bounds__(512, 2) void gemm256(
    const bf16* __restrict__ A, const bf16* __restrict__ Bt,
    const float* __restrict__ b0, const float* __restrict__ b1,
    const float* __restrict__ b2, int sp1, int sp2, int nscale, float scale,
    void* __restrict__ Cout, int N, int K)
{
  __shared__ bf16 As[2][256 * 64];
  __shared__ bf16 Bs[2][NF * 64 * 64];

  const int tid = threadIdx.x, lane = tid & 63;
  const int wid = tid >> 6;
  const int wr = wid >> 1, wc = wid & 1;     // 4M x 2N wave grid
  const int l31 = lane & 31, hi2 = lane >> 5;
  const int rx = l31 & 7;

  // XCD-chunked swizzle over the fixed 16x16 grid
  const int bid = blockIdx.y * 16 + blockIdx.x;
  const int swz = (bid & 7) * 32 + (bid >> 3);
  const int m0 = (swz >> 4) * 256, n0 = (swz & 15) * (NF * 64);

  // staging map: 512 threads x 16B; A: 4 loads (64 rows each), B: NF loads
  const int srow = tid >> 3;                 // 0..63
  const int schk = (tid & 7) ^ (srow & 7);   // pre-swizzled source chunk
  const bf16* aSrc = A  + (size_t)(m0 + srow) * K + schk * 8;
  const bf16* bSrc = Bt + (size_t)(n0 + srow) * K + schk * 8;
  const size_t rstep = (size_t)64 * K;

  f32x16 acc[2][NF] = {};                    // [m-tile][n-tile], 32x32 each

  const int NT = K / 64;                     // 32

#define G256_STAGE(T, BUF)                                            \
  {                                                                   \
    const bf16* a_ = aSrc + (T) * 64;                                 \
    _Pragma("unroll")                                                 \
    for (int j = 0; j < 4; ++j)                                       \
      gload_lds16(a_ + j * rstep, &As[BUF][j * 4096 + tid * 8]);      \
    const bf16* b_ = bSrc + (T) * 64;                                 \
    _Pragma("unroll")                                                 \
    for (int j = 0; j < NF; ++j)                                      \
      gload_lds16(b_ + j * rstep, &Bs[BUF][j * 4096 + tid * 8]);      \
  }

#define G256_WAITL()                                                  \
  if constexpr (NF == 3) asm volatile("s_waitcnt vmcnt(7)" ::: "memory"); \
  else                   asm volatile("s_waitcnt vmcnt(6)" ::: "memory");

#define G256_BODY(BUF)                                                \
  {                                                                   \
    _Pragma("unroll")                                                 \
    for (int ks = 0; ks < 4; ++ks) {                                  \
      bf16x8 af[2], bfv[NF];                                          \
      _Pragma("unroll")                                               \
      for (int m = 0; m < 2; ++m)                                     \
        af[m] = *(const bf16x8*)&As[BUF][(wr * 64 + m * 32 + l31) * 64 \
                                         + (((ks * 2 + hi2) ^ rx) * 8)]; \
      _Pragma("unroll")                                               \
      for (int n = 0; n < NF; ++n)                                    \
        bfv[n] = *(const bf16x8*)&Bs[BUF][(wc * (NF * 32) + n * 32 + l31) * 64 \
                                          + (((ks * 2 + hi2) ^ rx) * 8)]; \
      __builtin_amdgcn_s_setprio(1);                                  \
      _Pragma("unroll")                                               \
      for (int m = 0; m < 2; ++m)                                     \
        _Pragma("unroll")                                             \
        for (int n = 0; n < NF; ++n)                                  \
          acc[m][n] = __builtin_amdgcn_mfma_f32_32x32x16_bf16(        \
              af[m], bfv[n], acc[m][n], 0, 0, 0);                     \
      __builtin_amdgcn_s_setprio(0);                                  \
    }                                                                 \
  }

  // prologue: stage tiles 0,1; wait tile 0; sync
  G256_STAGE(0, 0)
  G256_STAGE(1, 1)
  G256_WAITL()
  __builtin_amdgcn_sched_barrier(0);
  __builtin_amdgcn_s_barrier();
  __builtin_amdgcn_sched_barrier(0);

  for (int t = 0; t < NT; t += 2) {
    #pragma unroll
    for (int u = 0; u < 2; ++u) {            // tile tt = t+u lives in buf u
      G256_BODY(u)
      __builtin_amdgcn_sched_barrier(0);
      __builtin_amdgcn_s_barrier();          // all waves done reading buf u
      __builtin_amdgcn_sched_barrier(0);
      const int tt = t + u;
      if (tt < NT - 2) {
        G256_STAGE(tt + 2, u)                // overwrite buf u with tile tt+2
        G256_WAITL()                         // tile tt+1's loads now complete
      } else {
        asm volatile("s_waitcnt vmcnt(0)" ::: "memory");
      }
      __builtin_amdgcn_sched_barrier(0);
      __builtin_amdgcn_s_barrier();          // tile tt+1 visible block-wide
      __builtin_amdgcn_sched_barrier(0);
    }
  }

#undef G256_STAGE
#undef G256_WAITL
#undef G256_BODY

  // epilogue: bias + scale + store (32x32 C/D layout: col=lane&31,
  // row=(r&3)+8*(r>>2)+4*hi2 — m101-verified)
  const int cb = n0 + wc * (NF * 32) + l31;
  #pragma unroll
  for (int n = 0; n < NF; ++n) {
    const int col = cb + n * 32;
    float bv;
    if (col < sp1)      bv = b0[col];
    else if (col < sp2) bv = b1[col - sp1];
    else                bv = b2[col - sp2];
    const float scl = (col < nscale) ? scale : 1.0f;
    #pragma unroll
    for (int m = 0; m < 2; ++m) {
      const int rb = m0 + wr * 64 + m * 32 + 4 * hi2;
      #pragma unroll
      for (int r = 0; r < 16; ++r) {
        const int row = rb + (r & 3) + 8 * (r >> 2);
        const float v = (acc[m][n][r] + bv) * scl;
        if (OUT_BF16) ((bf16*)Cout)[(size_t)row * N + col] = (bf16)v;
        else          ((float*)Cout)[(size_t)row * N + col] = v;
      }
    }
  }
}

// ---------------- flash attention (EXACT R5-lineage kernel — frozen) ----------------
__global__ __launch_bounds__(256) void attn_kernel(
    const bf16* __restrict__ QKV, const bf16* __restrict__ Vtg, bf16* __restrict__ ctx)
{
  __shared__ bf16 smem[4][64 * 64];   // [0..1] K dbuf, [2..3] Vt dbuf; 32 KB

  const int tid = threadIdx.x, lane = tid & 63, wid = tid >> 6;
  const int l31 = lane & 31, hi = lane >> 5;
  const int qt = blockIdx.x & 15;
  const int bh = blockIdx.x >> 4;
  const int h = bh & 31, b = bh >> 5, kvh = h >> 2;

  const bf16* gK = QKV + (size_t)b * SEQ * QKV_N + 2048 + kvh * 64;
  const bf16* gV = Vtg + (size_t)(b * 8 + kvh) * 64 * SEQ;

  const int sr  = lane >> 3;            // staging row within 8-row group
  const int scn = (lane & 7) ^ sr;      // pre-swizzled logical chunk

  bf16x8 qf[4];
  {
    const bf16* qp = QKV + (size_t)(b * SEQ + qt * 128 + wid * 32 + l31) * QKV_N + h * 64 + hi * 8;
    #pragma unroll
    for (int kt = 0; kt < 4; ++kt) qf[kt] = *(const bf16x8*)(qp + kt * 16);
  }

  bf16x8 onesv;
  #pragma unroll
  for (int j = 0; j < 8; ++j) onesv[j] = (bf16)1.0f;

  f32x16 o0 = {}, o1 = {};
  f32x16 lacc = {};

  const int row0 = (wid * 2 + 0) * 8 + sr;
  const int row1 = (wid * 2 + 1) * 8 + sr;
  const bf16* pK0 = gK + (size_t)row0 * QKV_N + scn * 8;
  const bf16* pK1 = gK + (size_t)row1 * QKV_N + scn * 8;
  const bf16* pV0 = gV + (size_t)row0 * SEQ + scn * 8;
  const bf16* pV1 = gV + (size_t)row1 * SEQ + scn * 8;

  gload_lds16(pK0, &smem[0][(wid * 2 + 0) * 512]);
  gload_lds16(pK1, &smem[0][(wid * 2 + 1) * 512]);
  gload_lds16(pV0, &smem[2][(wid * 2 + 0) * 512]);
  gload_lds16(pV1, &smem[2][(wid * 2 + 1) * 512]);
  pK0 += (size_t)64 * QKV_N; pK1 += (size_t)64 * QKV_N; pV0 += 64; pV1 += 64;
  __syncthreads();

  const int rx = l31 & 7;

  for (int it = 0; it < 32; ++it) {
    const int cur = it & 1;
    if (it < 31) {
      gload_lds16(pK0, &smem[cur ^ 1][(wid * 2 + 0) * 512]);
      gload_lds16(pK1, &smem[cur ^ 1][(wid * 2 + 1) * 512]);
      gload_lds16(pV0, &smem[2 + (cur ^ 1)][(wid * 2 + 0) * 512]);
      gload_lds16(pV1, &smem[2 + (cur ^ 1)][(wid * 2 + 1) * 512]);
      pK0 += (size_t)64 * QKV_N; pK1 += (size_t)64 * QKV_N; pV0 += 64; pV1 += 64;
    }
    const bf16* Kb = smem[cur];
    const bf16* Vb = smem[2 + cur];

    bf16x8 kf[8];
    #pragma unroll
    for (int kt = 0; kt < 4; ++kt) {
      const int ck = hi + 2 * kt;
      kf[kt]     = *(const bf16x8*)(Kb + (size_t)l31 * 64        + ((ck ^ rx) * 8));
      kf[kt + 4] = *(const bf16x8*)(Kb + (size_t)(32 + l31) * 64 + ((ck ^ rx) * 8));
    }
    f32x16 s0v = {}, s1v = {};
    __builtin_amdgcn_s_setprio(1);
    #pragma unroll
    for (int kt = 0; kt < 4; ++kt) {
      s0v = __builtin_amdgcn_mfma_f32_32x32x16_bf16(kf[kt],     qf[kt], s0v, 0, 0, 0);
      s1v = __builtin_amdgcn_mfma_f32_32x32x16_bf16(kf[kt + 4], qf[kt], s1v, 0, 0, 0);
    }
    __builtin_amdgcn_s_setprio(0);

    bf16x8 vf[8];
    #pragma unroll
    for (int s = 0; s < 4; ++s) {
      const int ck = hi + 2 * s;
      vf[s]     = *(const bf16x8*)(Vb + (size_t)l31 * 64        + ((ck ^ rx) * 8));
      vf[s + 4] = *(const bf16x8*)(Vb + (size_t)(32 + l31) * 64 + ((ck ^ rx) * 8));
    }

    #pragma unroll
    for (int r = 0; r < 16; ++r) { s0v[r] = EXP2(s0v[r]); s1v[r] = EXP2(s1v[r]); }

    #pragma unroll
    for (int s = 0; s < 4; ++s) {
      const f32x16& sv = (s < 2) ? s0v : s1v;
      const int rb = (s & 1) * 8;
      uint32_t Aw = pk2(sv[rb + 0], sv[rb + 1]);
      uint32_t Bw = pk2(sv[rb + 2], sv[rb + 3]);
      uint32_t Cw = pk2(sv[rb + 4], sv[rb + 5]);
      uint32_t Dw = pk2(sv[rb + 6], sv[rb + 7]);
      union { uint32_t w[4]; bf16x8 v; } pf;
#if __has_builtin(__builtin_amdgcn_permlane32_swap)
      auto rA = __builtin_amdgcn_permlane32_swap(Aw, Cw, false, false);
      auto rB = __builtin_amdgcn_permlane32_swap(Bw, Dw, false, false);
      pf.w[0] = rA[0]; pf.w[1] = rB[0]; pf.w[2] = rA[1]; pf.w[3] = rB[1];
#else
      uint32_t U = hi ? Aw : Cw;
      uint32_t W = hi ? Bw : Dw;
      uint32_t pU = (uint32_t)__shfl_xor((int)U, 32);
      uint32_t pW = (uint32_t)__shfl_xor((int)W, 32);
      pf.w[0] = hi ? pU : Aw;
      pf.w[1] = hi ? pW : Bw;
      pf.w[2] = hi ? Cw : pU;
      pf.w[3] = hi ? Dw : pW;
#endif
      __builtin_amdgcn_s_setprio(1);
      o0 = __builtin_amdgcn_mfma_f32_32x32x16_bf16(vf[s],     pf.v, o0, 0, 0, 0);
      o1 = __builtin_amdgcn_mfma_f32_32x32x16_bf16(vf[s + 4], pf.v, o1, 0, 0, 0);
      lacc = __builtin_amdgcn_mfma_f32_32x32x16_bf16(onesv,   pf.v, lacc, 0, 0, 0);
      __builtin_amdgcn_s_setprio(0);
    }
    __syncthreads();
  }

  const float inv = 1.0f / lacc[0];
  o0 *= inv; o1 *= inv;

  uint32_t* ot = (uint32_t*)((bf16*)smem + wid * 2304);
  #pragma unroll
  for (int r = 0; r < 16; r += 2) {
    const int d = (r & 3) + 8 * (r >> 2) + 4 * hi;
    ot[l31 * 36 + (d >> 1)]        = pk2(o0[r], o0[r + 1]);
    ot[l31 * 36 + ((32 + d) >> 1)] = pk2(o1[r], o1[r + 1]);
  }
  __syncthreads();
  {
    const int q2 = lane >> 1, hf = lane & 1;
    const bf16* src = (const bf16*)smem + wid * 2304 + q2 * 72 + hf * 32;
    bf16* dst = ctx + (size_t)(b * SEQ + qt * 128 + wid * 32 + q2) * D_MODEL + h * 64 + hf * 32;
    #pragma unroll
    for (int k = 0; k < 4; ++k)
      *(bf16x8*)(dst + k * 8) = *(const bf16x8*)(src + k * 8);
  }
}

// ---------------------------------------------------------------------------
extern "C" void kernel_launch(void* const* d_in, const int* in_sizes, int n_in,
                              void* d_out, int out_size, void* d_ws, size_t ws_size,
                              hipStream_t stream) {
  const float* x  = (const float*)d_in[0];
  const float* Wq = (const float*)d_in[1];
  const float* bq = (const float*)d_in[2];
  const float* Wk = (const float*)d_in[3];
  const float* bk = (const float*)d_in[4];
  const float* Wv = (const float*)d_in[5];
  const float* bv = (const float*)d_in[6];
  const float* Wo = (const float*)d_in[7];
  const float* bo = (const float*)d_in[8];
  float* out = (float*)d_out;

  char* ws = (char*)d_ws;
  size_t off = 0;
  bf16* xb   = (bf16*)(ws + off); off += (size_t)MTOT * D_MODEL * 2;       // x bf16
  bf16* Wall = (bf16*)(ws + off); off += (size_t)QKV_N * D_MODEL * 2;      // [Wq^T;Wk^T;Wv^T]
  bf16* Wot  = (bf16*)(ws + off); off += (size_t)D_MODEL * D_MODEL * 2;    // Wo^T
  bf16* QKV  = (bf16*)(ws + off); off += (size_t)MTOT * QKV_N * 2;         // [Q|K|V]
  bf16* ctx  = (bf16*)(ws + off); off += (size_t)MTOT * D_MODEL * 2;       // attn out
  bf16* Vtg  = (bf16*)(ws + off); off += (size_t)16 * 64 * SEQ * 2;        // V^T

  // 1) x -> bf16
  {
    int n = MTOT * D_MODEL;
    cvt_f32_bf16<<<n / 4 / 256, 256, 0, stream>>>(x, xb, n);
  }
  // 2) all weight transposes, one launch
  transpose_all<<<dim3(32, 32, 4), 256, 0, stream>>>(Wq, Wk, Wv, Wo, Wall, Wot);

  // 3) fused QKV projection: BM=256 x BN=192 -> 16x16 = 256 blocks (full fill)
  gemm256<3, 1><<<dim3(16, 16), 512, 0, stream>>>(
      xb, Wall, bq, bk, bv, 2048, 2560, 2048, QSCALE, QKV, QKV_N, D_MODEL);

  // 3b) V -> V^T
  transpose_v<<<dim3(SEQ / 64, 16), 256, 0, stream>>>(QKV, Vtg);

  // 4) attention
  attn_kernel<<<dim3((SEQ / 128) * BATCH * 32), 256, 0, stream>>>(QKV, Vtg, ctx);

  // 5) output projection: BM=256 x BN=128 -> 16x16 = 256 blocks (full fill)
  gemm256<2, 0><<<dim3(16, 16), 512, 0, stream>>>(
      ctx, Wot, bo, bo, bo, 2048, 2048, 0, 1.0f, out, D_MODEL, D_MODEL);
}

// Round 15
// 219.112 us; speedup vs baseline: 1.0937x; 1.0736x over previous
//
#include <hip/hip_runtime.h>
#include <hip/hip_bf16.h>
#include <stdint.h>

typedef __bf16 bf16;
typedef __bf16 bf16x8 __attribute__((ext_vector_type(8)));
typedef float  f32x2  __attribute__((ext_vector_type(2)));
typedef float  f32x4  __attribute__((ext_vector_type(4)));
typedef float  f32x16 __attribute__((ext_vector_type(16)));

#define D_MODEL 2048
#define KV_DIM  512
#define SEQ     2048
#define BATCH   2
#define MTOT    (BATCH*SEQ)            // 4096
#define QKV_N   3072                   // 2048 Q + 512 K + 512 V
#define QSCALE  (0.125f*1.44269504088896f)  // 1/sqrt(64) * log2(e)

#if __has_builtin(__builtin_amdgcn_exp2f)
#define EXP2(x) __builtin_amdgcn_exp2f(x)
#else
#define EXP2(x) exp2f(x)
#endif

// ---------------- f32 -> bf16 convert (vectorized x4) ----------------
__global__ __launch_bounds__(256) void cvt_f32_bf16(const float* __restrict__ in,
                                                    bf16* __restrict__ out, int n) {
  int i = (blockIdx.x * 256 + threadIdx.x) * 4;
  if (i < n) {
    float4 v = *reinterpret_cast<const float4*>(in + i);
    bf16 o[4] = {(bf16)v.x, (bf16)v.y, (bf16)v.z, (bf16)v.w};
    *reinterpret_cast<uint64_t*>(out + i) = *reinterpret_cast<const uint64_t*>(o);
  }
}

// ------------- all 4 weight transposes in one launch (z selects matrix) -------------
__global__ __launch_bounds__(256) void transpose_all(
    const float* __restrict__ Wq, const float* __restrict__ Wk,
    const float* __restrict__ Wv, const float* __restrict__ Wo,
    bf16* __restrict__ Wall, bf16* __restrict__ Wot) {
  const int z = blockIdx.z;
  const float* W; bf16* dst; int N;
  if (z == 0)      { W = Wq; dst = Wall;                          N = 2048; }
  else if (z == 1) { W = Wk; dst = Wall + (size_t)2048 * 2048;    N = 512;  }
  else if (z == 2) { W = Wv; dst = Wall + (size_t)2560 * 2048;    N = 512;  }
  else             { W = Wo; dst = Wot;                           N = 2048; }
  const int n0 = blockIdx.x * 64, k0 = blockIdx.y * 64;
  if (n0 >= N) return;
  __shared__ float tile[64][65];
  const int tx = threadIdx.x & 63;
  const int ty = threadIdx.x >> 6;   // 0..3
  #pragma unroll
  for (int i = ty; i < 64; i += 4)
    tile[i][tx] = W[(size_t)(k0 + i) * N + n0 + tx];
  __syncthreads();
  #pragma unroll
  for (int i = ty; i < 64; i += 4)
    dst[(size_t)(n0 + i) * 2048 + k0 + tx] = (bf16)tile[tx][i];
}

// ------------- transpose V: QKV[token][2560..3071] -> Vtg[(b*8+kvh)*64+d][S] -------------
__global__ __launch_bounds__(256) void transpose_v(const bf16* __restrict__ QKV,
                                                   bf16* __restrict__ Vtg) {
  __shared__ bf16 t[64][72];
  const int st = blockIdx.x;        // s-tile 0..31
  const int bk = blockIdx.y;        // 0..15 = b*8+kvh
  const int b = bk >> 3, kvh = bk & 7;
  const int tid = threadIdx.x;
  const int r = tid >> 2, c = (tid & 3) * 16;
  const bf16* src = QKV + (size_t)(b * SEQ + st * 64 + r) * QKV_N + 2560 + kvh * 64 + c;
  *(bf16x8*)&t[r][c]     = *(const bf16x8*)src;
  *(bf16x8*)&t[r][c + 8] = *(const bf16x8*)(src + 8);
  __syncthreads();
  bf16 tmp[16];
  #pragma unroll
  for (int j = 0; j < 16; ++j) tmp[j] = t[c + j][r];
  bf16* dst = Vtg + (size_t)(bk * 64 + r) * SEQ + st * 64 + c;
  *(bf16x8*)dst       = *(const bf16x8*)tmp;
  *(bf16x8*)(dst + 8) = *(const bf16x8*)(tmp + 8);
}

// ---------------- async global->LDS, 16B per lane ----------------
__device__ __forceinline__ void gload_lds16(const bf16* g, bf16* l) {
  __builtin_amdgcn_global_load_lds(
      (const __attribute__((address_space(1))) uint32_t*)g,
      (__attribute__((address_space(3))) uint32_t*)l, 16, 0, 0);
}

__device__ __forceinline__ uint32_t pk2(float a, float b) {
  union { bf16 h[2]; uint32_t u; } v;
  v.h[0] = (bf16)a; v.h[1] = (bf16)b;
  return v.u;
}

// ---------------- deep-pipelined GEMM (R12-exact, frozen) ----------------
template<int NF, int OUT_BF16>
__global__ __launch_bounds__(512, 2) void gemm256(
    const bf16* __restrict__ A, const bf16* __restrict__ Bt,
    const float* __restrict__ b0, const float* __restrict__ b1,
    const float* __restrict__ b2, int sp1, int sp2, int nscale, float scale,
    void* __restrict__ Cout, int N, int K)
{
  __shared__ bf16 As[2][256 * 64];
  __shared__ bf16 Bs[2][NF * 64 * 64];

  const int tid = threadIdx.x, lane = tid & 63;
  const int wid = tid >> 6;
  const int wr = wid >> 1, wc = wid & 1;     // 4M x 2N wave grid
  const int l31 = lane & 31, hi2 = lane >> 5;
  const int rx = l31 & 7;

  const int bid = blockIdx.y * 16 + blockIdx.x;
  const int swz = (bid & 7) * 32 + (bid >> 3);
  const int m0 = (swz >> 4) * 256, n0 = (swz & 15) * (NF * 64);

  const int srow = tid >> 3;                 // 0..63
  const int schk = (tid & 7) ^ (srow & 7);   // pre-swizzled source chunk
  const bf16* aSrc = A  + (size_t)(m0 + srow) * K + schk * 8;
  const bf16* bSrc = Bt + (size_t)(n0 + srow) * K + schk * 8;
  const size_t rstep = (size_t)64 * K;

  f32x16 acc[2][NF] = {};

  const int NT = K / 64;                     // 32

#define G256_STAGE(T, BUF)                                            \
  {                                                                   \
    const bf16* a_ = aSrc + (T) * 64;                                 \
    _Pragma("unroll")                                                 \
    for (int j = 0; j < 4; ++j)                                       \
      gload_lds16(a_ + j * rstep, &As[BUF][j * 4096 + tid * 8]);      \
    const bf16* b_ = bSrc + (T) * 64;                                 \
    _Pragma("unroll")                                                 \
    for (int j = 0; j < NF; ++j)                                      \
      gload_lds16(b_ + j * rstep, &Bs[BUF][j * 4096 + tid * 8]);      \
  }

#define G256_WAITL()                                                  \
  if constexpr (NF == 3) asm volatile("s_waitcnt vmcnt(7)" ::: "memory"); \
  else                   asm volatile("s_waitcnt vmcnt(6)" ::: "memory");

#define G256_BODY(BUF)                                                \
  {                                                                   \
    _Pragma("unroll")                                                 \
    for (int ks = 0; ks < 4; ++ks) {                                  \
      bf16x8 af[2], bfv[NF];                                          \
      _Pragma("unroll")                                               \
      for (int m = 0; m < 2; ++m)                                     \
        af[m] = *(const bf16x8*)&As[BUF][(wr * 64 + m * 32 + l31) * 64 \
                                         + (((ks * 2 + hi2) ^ rx) * 8)]; \
      _Pragma("unroll")                                               \
      for (int n = 0; n < NF; ++n)                                    \
        bfv[n] = *(const bf16x8*)&Bs[BUF][(wc * (NF * 32) + n * 32 + l31) * 64 \
                                          + (((ks * 2 + hi2) ^ rx) * 8)]; \
      __builtin_amdgcn_s_setprio(1);                                  \
      _Pragma("unroll")                                               \
      for (int m = 0; m < 2; ++m)                                     \
        _Pragma("unroll")                                             \
        for (int n = 0; n < NF; ++n)                                  \
          acc[m][n] = __builtin_amdgcn_mfma_f32_32x32x16_bf16(        \
              af[m], bfv[n], acc[m][n], 0, 0, 0);                     \
      __builtin_amdgcn_s_setprio(0);                                  \
    }                                                                 \
  }

  G256_STAGE(0, 0)
  G256_STAGE(1, 1)
  G256_WAITL()
  __builtin_amdgcn_sched_barrier(0);
  __builtin_amdgcn_s_barrier();
  __builtin_amdgcn_sched_barrier(0);

  for (int t = 0; t < NT; t += 2) {
    #pragma unroll
    for (int u = 0; u < 2; ++u) {
      G256_BODY(u)
      __builtin_amdgcn_sched_barrier(0);
      __builtin_amdgcn_s_barrier();
      __builtin_amdgcn_sched_barrier(0);
      const int tt = t + u;
      if (tt < NT - 2) {
        G256_STAGE(tt + 2, u)
        G256_WAITL()
      } else {
        asm volatile("s_waitcnt vmcnt(0)" ::: "memory");
      }
      __builtin_amdgcn_sched_barrier(0);
      __builtin_amdgcn_s_barrier();
      __builtin_amdgcn_sched_barrier(0);
    }
  }

#undef G256_STAGE
#undef G256_WAITL
#undef G256_BODY

  const int cb = n0 + wc * (NF * 32) + l31;
  #pragma unroll
  for (int n = 0; n < NF; ++n) {
    const int col = cb + n * 32;
    float bv;
    if (col < sp1)      bv = b0[col];
    else if (col < sp2) bv = b1[col - sp1];
    else                bv = b2[col - sp2];
    const float scl = (col < nscale) ? scale : 1.0f;
    #pragma unroll
    for (int m = 0; m < 2; ++m) {
      const int rb = m0 + wr * 64 + m * 32 + 4 * hi2;
      #pragma unroll
      for (int r = 0; r < 16; ++r) {
        const int row = rb + (r & 3) + 8 * (r >> 2);
        const float v = (acc[m][n][r] + bv) * scl;
        if (OUT_BF16) ((bf16*)Cout)[(size_t)row * N + col] = (bf16)v;
        else          ((float*)Cout)[(size_t)row * N + col] = v;
      }
    }
  }
}

// ---------------- flash attention, R15: 2 q-sets (64 q-rows) per wave ----------------
// 4 waves x 64 q-rows = 256 q/block; grid 512 = 2 blocks/CU. KVBLK=64.
// kf/vf/staging/barrier amortized over 2x MFMA work per iteration.
// __launch_bounds__(256,2): 256-reg budget for ~210-235 live regs.
__global__ __launch_bounds__(256, 2) void attn_kernel(
    const bf16* __restrict__ QKV, const bf16* __restrict__ Vtg, bf16* __restrict__ ctx)
{
  __shared__ bf16 smem[4][64 * 64];   // [0..1] K dbuf, [2..3] Vt dbuf; 32 KB

  const int tid = threadIdx.x, lane = tid & 63, wid = tid >> 6;
  const int l31 = lane & 31, hi = lane >> 5;
  const int qt = blockIdx.x & 7;      // 8 q-tiles of 256 rows
  const int bh = blockIdx.x >> 3;
  const int h = bh & 31, b = bh >> 5, kvh = h >> 2;

  const bf16* gK = QKV + (size_t)b * SEQ * QKV_N + 2048 + kvh * 64;
  const bf16* gV = Vtg + (size_t)(b * 8 + kvh) * 64 * SEQ;

  const int sr  = lane >> 3;            // staging row within 8-row group
  const int scn = (lane & 7) ^ sr;      // pre-swizzled logical chunk

  // Q fragments for both q-sets: set0 rows qt*256 + wid*64 + l31, set1 +32
  bf16x8 qf[4], qf2[4];
  {
    const bf16* qp = QKV + (size_t)(b * SEQ + qt * 256 + wid * 64 + l31) * QKV_N + h * 64 + hi * 8;
    #pragma unroll
    for (int kt = 0; kt < 4; ++kt) qf[kt]  = *(const bf16x8*)(qp + kt * 16);
    const bf16* qp2 = qp + (size_t)32 * QKV_N;
    #pragma unroll
    for (int kt = 0; kt < 4; ++kt) qf2[kt] = *(const bf16x8*)(qp2 + kt * 16);
  }

  bf16x8 onesv;
  #pragma unroll
  for (int j = 0; j < 8; ++j) onesv[j] = (bf16)1.0f;

  f32x16 o0 = {}, o1 = {}, o2 = {}, o3 = {};
  f32x16 lacc = {}, lacc2 = {};

  const int row0 = (wid * 2 + 0) * 8 + sr;
  const int row1 = (wid * 2 + 1) * 8 + sr;
  const bf16* pK0 = gK + (size_t)row0 * QKV_N + scn * 8;
  const bf16* pK1 = gK + (size_t)row1 * QKV_N + scn * 8;
  const bf16* pV0 = gV + (size_t)row0 * SEQ + scn * 8;
  const bf16* pV1 = gV + (size_t)row1 * SEQ + scn * 8;

  gload_lds16(pK0, &smem[0][(wid * 2 + 0) * 512]);
  gload_lds16(pK1, &smem[0][(wid * 2 + 1) * 512]);
  gload_lds16(pV0, &smem[2][(wid * 2 + 0) * 512]);
  gload_lds16(pV1, &smem[2][(wid * 2 + 1) * 512]);
  pK0 += (size_t)64 * QKV_N; pK1 += (size_t)64 * QKV_N; pV0 += 64; pV1 += 64;
  __syncthreads();

  const int rx = l31 & 7;

// pack + PV for one q-set (consumes SA/SB, accumulates OA/OB/LC)
#define PV_SET(SA, SB, OA, OB, LC)                                        \
    _Pragma("unroll")                                                     \
    for (int s = 0; s < 4; ++s) {                                         \
      const f32x16& sv = (s < 2) ? SA : SB;                               \
      const int rb = (s & 1) * 8;                                         \
      uint32_t Aw = pk2(sv[rb + 0], sv[rb + 1]);                          \
      uint32_t Bw = pk2(sv[rb + 2], sv[rb + 3]);                          \
      uint32_t Cw = pk2(sv[rb + 4], sv[rb + 5]);                          \
      uint32_t Dw = pk2(sv[rb + 6], sv[rb + 7]);                          \
      union { uint32_t w[4]; bf16x8 v; } pf;                              \
      auto rA = __builtin_amdgcn_permlane32_swap(Aw, Cw, false, false);   \
      auto rB = __builtin_amdgcn_permlane32_swap(Bw, Dw, false, false);   \
      pf.w[0] = rA[0]; pf.w[1] = rB[0]; pf.w[2] = rA[1]; pf.w[3] = rB[1]; \
      __builtin_amdgcn_s_setprio(1);                                      \
      OA = __builtin_amdgcn_mfma_f32_32x32x16_bf16(vf[s],     pf.v, OA, 0, 0, 0); \
      OB = __builtin_amdgcn_mfma_f32_32x32x16_bf16(vf[s + 4], pf.v, OB, 0, 0, 0); \
      LC = __builtin_amdgcn_mfma_f32_32x32x16_bf16(onesv,     pf.v, LC, 0, 0, 0); \
      __builtin_amdgcn_s_setprio(0);                                      \
    }

  for (int it = 0; it < 32; ++it) {
    const int cur = it & 1;
    if (it < 31) {
      gload_lds16(pK0, &smem[cur ^ 1][(wid * 2 + 0) * 512]);
      gload_lds16(pK1, &smem[cur ^ 1][(wid * 2 + 1) * 512]);
      gload_lds16(pV0, &smem[2 + (cur ^ 1)][(wid * 2 + 0) * 512]);
      gload_lds16(pV1, &smem[2 + (cur ^ 1)][(wid * 2 + 1) * 512]);
      pK0 += (size_t)64 * QKV_N; pK1 += (size_t)64 * QKV_N; pV0 += 64; pV1 += 64;
    }
    const bf16* Kb = smem[cur];
    const bf16* Vb = smem[2 + cur];

    // ---- QK^T for both q-sets (kf loaded once) ----
    bf16x8 kf[8];
    #pragma unroll
    for (int kt = 0; kt < 4; ++kt) {
      const int ck = hi + 2 * kt;
      kf[kt]     = *(const bf16x8*)(Kb + (size_t)l31 * 64        + ((ck ^ rx) * 8));
      kf[kt + 4] = *(const bf16x8*)(Kb + (size_t)(32 + l31) * 64 + ((ck ^ rx) * 8));
    }
    f32x16 s0v = {}, s1v = {}, s2v = {}, s3v = {};
    __builtin_amdgcn_s_setprio(1);
    #pragma unroll
    for (int kt = 0; kt < 4; ++kt) {
      s0v = __builtin_amdgcn_mfma_f32_32x32x16_bf16(kf[kt],     qf[kt],  s0v, 0, 0, 0);
      s1v = __builtin_amdgcn_mfma_f32_32x32x16_bf16(kf[kt + 4], qf[kt],  s1v, 0, 0, 0);
      s2v = __builtin_amdgcn_mfma_f32_32x32x16_bf16(kf[kt],     qf2[kt], s2v, 0, 0, 0);
      s3v = __builtin_amdgcn_mfma_f32_32x32x16_bf16(kf[kt + 4], qf2[kt], s3v, 0, 0, 0);
    }
    __builtin_amdgcn_s_setprio(0);

    // ---- V fragments (loaded once; latency hides under exp) ----
    bf16x8 vf[8];
    #pragma unroll
    for (int s = 0; s < 4; ++s) {
      const int ck = hi + 2 * s;
      vf[s]     = *(const bf16x8*)(Vb + (size_t)l31 * 64        + ((ck ^ rx) * 8));
      vf[s + 4] = *(const bf16x8*)(Vb + (size_t)(32 + l31) * 64 + ((ck ^ rx) * 8));
    }

    // ---- P = exp2(S), both sets ----
    #pragma unroll
    for (int r = 0; r < 16; ++r) {
      s0v[r] = EXP2(s0v[r]); s1v[r] = EXP2(s1v[r]);
      s2v[r] = EXP2(s2v[r]); s3v[r] = EXP2(s3v[r]);
    }

    // ---- PV + row-sum, both sets ----
    PV_SET(s0v, s1v, o0, o1, lacc)
    PV_SET(s2v, s3v, o2, o3, lacc2)
    __syncthreads();
  }
#undef PV_SET

  // ---- normalize + write, set by set (ot LDS region reused with barriers) ----
#define WRITE_SET(OA, OB, LC, QOFF)                                        \
  {                                                                        \
    const float inv = 1.0f / LC[0];                                        \
    OA *= inv; OB *= inv;                                                  \
    uint32_t* ot = (uint32_t*)((bf16*)smem + wid * 2304);                  \
    _Pragma("unroll")                                                      \
    for (int r = 0; r < 16; r += 2) {                                      \
      const int d = (r & 3) + 8 * (r >> 2) + 4 * hi;                       \
      ot[l31 * 36 + (d >> 1)]        = pk2(OA[r], OA[r + 1]);              \
      ot[l31 * 36 + ((32 + d) >> 1)] = pk2(OB[r], OB[r + 1]);              \
    }                                                                      \
    __syncthreads();                                                       \
    {                                                                      \
      const int q2 = lane >> 1, hf = lane & 1;                             \
      const bf16* src = (const bf16*)smem + wid * 2304 + q2 * 72 + hf * 32;\
      bf16* dst = ctx + (size_t)(b * SEQ + qt * 256 + wid * 64 + (QOFF) + q2) * D_MODEL \
                      + h * 64 + hf * 32;                                  \
      _Pragma("unroll")                                                    \
      for (int k = 0; k < 4; ++k)                                          \
        *(bf16x8*)(dst + k * 8) = *(const bf16x8*)(src + k * 8);           \
    }                                                                      \
    __syncthreads();                                                       \
  }

  WRITE_SET(o0, o1, lacc, 0)
  WRITE_SET(o2, o3, lacc2, 32)
#undef WRITE_SET
}

// ---------------------------------------------------------------------------
extern "C" void kernel_launch(void* const* d_in, const int* in_sizes, int n_in,
                              void* d_out, int out_size, void* d_ws, size_t ws_size,
                              hipStream_t stream) {
  const float* x  = (const float*)d_in[0];
  const float* Wq = (const float*)d_in[1];
  const float* bq = (const float*)d_in[2];
  const float* Wk = (const float*)d_in[3];
  const float* bk = (const float*)d_in[4];
  const float* Wv = (const float*)d_in[5];
  const float* bv = (const float*)d_in[6];
  const float* Wo = (const float*)d_in[7];
  const float* bo = (const float*)d_in[8];
  float* out = (float*)d_out;

  char* ws = (char*)d_ws;
  size_t off = 0;
  bf16* xb   = (bf16*)(ws + off); off += (size_t)MTOT * D_MODEL * 2;       // x bf16
  bf16* Wall = (bf16*)(ws + off); off += (size_t)QKV_N * D_MODEL * 2;      // [Wq^T;Wk^T;Wv^T]
  bf16* Wot  = (bf16*)(ws + off); off += (size_t)D_MODEL * D_MODEL * 2;    // Wo^T
  bf16* QKV  = (bf16*)(ws + off); off += (size_t)MTOT * QKV_N * 2;         // [Q|K|V]
  bf16* ctx  = (bf16*)(ws + off); off += (size_t)MTOT * D_MODEL * 2;       // attn out
  bf16* Vtg  = (bf16*)(ws + off); off += (size_t)16 * 64 * SEQ * 2;        // V^T

  // 1) x -> bf16
  {
    int n = MTOT * D_MODEL;
    cvt_f32_bf16<<<n / 4 / 256, 256, 0, stream>>>(x, xb, n);
  }
  // 2) all weight transposes, one launch
  transpose_all<<<dim3(32, 32, 4), 256, 0, stream>>>(Wq, Wk, Wv, Wo, Wall, Wot);

  // 3) fused QKV projection: BM=256 x BN=192 -> 16x16 = 256 blocks (full fill)
  gemm256<3, 1><<<dim3(16, 16), 512, 0, stream>>>(
      xb, Wall, bq, bk, bv, 2048, 2560, 2048, QSCALE, QKV, QKV_N, D_MODEL);

  // 3b) V -> V^T
  transpose_v<<<dim3(SEQ / 64, 16), 256, 0, stream>>>(QKV, Vtg);

  // 4) attention: 512 blocks (256 q-rows each), 2 blocks/CU
  attn_kernel<<<dim3((SEQ / 256) * BATCH * 32), 256, 0, stream>>>(QKV, Vtg, ctx);

  // 5) output projection: BM=256 x BN=128 -> 16x16 = 256 blocks (full fill)
  gemm256<2, 0><<<dim3(16, 16), 512, 0, stream>>>(
      ctx, Wot, bo, bo, bo, 2048, 2048, 0, 1.0f, out, D_MODEL, D_MODEL);
}

// Round 16
// 216.280 us; speedup vs baseline: 1.1080x; 1.0131x over previous
//
#include <hip/hip_runtime.h>
#include <hip/hip_bf16.h>
#include <stdint.h>

typedef __bf16 bf16;
typedef __bf16 bf16x8 __attribute__((ext_vector_type(8)));
typedef float  f32x2  __attribute__((ext_vector_type(2)));
typedef float  f32x4  __attribute__((ext_vector_type(4)));
typedef float  f32x16 __attribute__((ext_vector_type(16)));

#define D_MODEL 2048
#define KV_DIM  512
#define SEQ     2048
#define BATCH   2
#define MTOT    (BATCH*SEQ)            // 4096
#define QKV_N   3072                   // 2048 Q + 512 K + 512 V
#define QSCALE  (0.125f*1.44269504088896f)  // 1/sqrt(64) * log2(e)

#if __has_builtin(__builtin_amdgcn_exp2f)
#define EXP2(x) __builtin_amdgcn_exp2f(x)
#else
#define EXP2(x) exp2f(x)
#endif

// ---------------- f32 -> bf16 convert (vectorized x4) ----------------
__global__ __launch_bounds__(256) void cvt_f32_bf16(const float* __restrict__ in,
                                                    bf16* __restrict__ out, int n) {
  int i = (blockIdx.x * 256 + threadIdx.x) * 4;
  if (i < n) {
    float4 v = *reinterpret_cast<const float4*>(in + i);
    bf16 o[4] = {(bf16)v.x, (bf16)v.y, (bf16)v.z, (bf16)v.w};
    *reinterpret_cast<uint64_t*>(out + i) = *reinterpret_cast<const uint64_t*>(o);
  }
}

// ------------- all 4 weight transposes in one launch (z selects matrix) -------------
__global__ __launch_bounds__(256) void transpose_all(
    const float* __restrict__ Wq, const float* __restrict__ Wk,
    const float* __restrict__ Wv, const float* __restrict__ Wo,
    bf16* __restrict__ Wall, bf16* __restrict__ Wot) {
  const int z = blockIdx.z;
  const float* W; bf16* dst; int N;
  if (z == 0)      { W = Wq; dst = Wall;                          N = 2048; }
  else if (z == 1) { W = Wk; dst = Wall + (size_t)2048 * 2048;    N = 512;  }
  else if (z == 2) { W = Wv; dst = Wall + (size_t)2560 * 2048;    N = 512;  }
  else             { W = Wo; dst = Wot;                           N = 2048; }
  const int n0 = blockIdx.x * 64, k0 = blockIdx.y * 64;
  if (n0 >= N) return;
  __shared__ float tile[64][65];
  const int tx = threadIdx.x & 63;
  const int ty = threadIdx.x >> 6;   // 0..3
  #pragma unroll
  for (int i = ty; i < 64; i += 4)
    tile[i][tx] = W[(size_t)(k0 + i) * N + n0 + tx];
  __syncthreads();
  #pragma unroll
  for (int i = ty; i < 64; i += 4)
    dst[(size_t)(n0 + i) * 2048 + k0 + tx] = (bf16)tile[tx][i];
}

// ------------- transpose V: QKV[token][2560..3071] -> Vtg[(b*8+kvh)*64+d][S] -------------
__global__ __launch_bounds__(256) void transpose_v(const bf16* __restrict__ QKV,
                                                   bf16* __restrict__ Vtg) {
  __shared__ bf16 t[64][72];
  const int st = blockIdx.x;        // s-tile 0..31
  const int bk = blockIdx.y;        // 0..15 = b*8+kvh
  const int b = bk >> 3, kvh = bk & 7;
  const int tid = threadIdx.x;
  const int r = tid >> 2, c = (tid & 3) * 16;
  const bf16* src = QKV + (size_t)(b * SEQ + st * 64 + r) * QKV_N + 2560 + kvh * 64 + c;
  *(bf16x8*)&t[r][c]     = *(const bf16x8*)src;
  *(bf16x8*)&t[r][c + 8] = *(const bf16x8*)(src + 8);
  __syncthreads();
  bf16 tmp[16];
  #pragma unroll
  for (int j = 0; j < 16; ++j) tmp[j] = t[c + j][r];
  bf16* dst = Vtg + (size_t)(bk * 64 + r) * SEQ + st * 64 + c;
  *(bf16x8*)dst       = *(const bf16x8*)tmp;
  *(bf16x8*)(dst + 8) = *(const bf16x8*)(tmp + 8);
}

// ---------------- async global->LDS, 16B per lane ----------------
__device__ __forceinline__ void gload_lds16(const bf16* g, bf16* l) {
  __builtin_amdgcn_global_load_lds(
      (const __attribute__((address_space(1))) uint32_t*)g,
      (__attribute__((address_space(3))) uint32_t*)l, 16, 0, 0);
}

__device__ __forceinline__ uint32_t pk2(float a, float b) {
  union { bf16 h[2]; uint32_t u; } v;
  v.h[0] = (bf16)a; v.h[1] = (bf16)b;
  return v.u;
}

// ---------------- deep-pipelined GEMM: C[4096][N] = A @ Bt^T + bias ----------------
// R16: 8-phase interleave (m201 template). Per K-tile, 4 sub-phases:
// {ds_read ks_i || stage-issue(next tile -> other buf) -> barrier -> MFMA -> barrier}.
// Staging front-loaded (A in ks0, B in ks1); one vmcnt(0) at tile end (loads had
// >=3 phases to land). Geometry/bounds identical to R12 (proven no-spill):
// BM=256, BN=NF*64; 8 waves 4Mx2N; mfma_32x32x16; __launch_bounds__(512,2).
template<int NF, int OUT_BF16>
__global__ __launch_bounds__(512, 2) void gemm256(
    const bf16* __restrict__ A, const bf16* __restrict__ Bt,
    const float* __restrict__ b0, const float* __restrict__ b1,
    const float* __restrict__ b2, int sp1, int sp2, int nscale, float scale,
    void* __restrict__ Cout, int N, int K)
{
  __shared__ bf16 As[2][256 * 64];
  __shared__ bf16 Bs[2][NF * 64 * 64];

  const int tid = threadIdx.x, lane = tid & 63;
  const int wid = tid >> 6;
  const int wr = wid >> 1, wc = wid & 1;     // 4M x 2N wave grid
  const int l31 = lane & 31, hi2 = lane >> 5;
  const int rx = l31 & 7;

  const int bid = blockIdx.y * 16 + blockIdx.x;
  const int swz = (bid & 7) * 32 + (bid >> 3);
  const int m0 = (swz >> 4) * 256, n0 = (swz & 15) * (NF * 64);

  const int srow = tid >> 3;                 // 0..63
  const int schk = (tid & 7) ^ (srow & 7);   // pre-swizzled source chunk
  const bf16* aSrc = A  + (size_t)(m0 + srow) * K + schk * 8;
  const bf16* bSrc = Bt + (size_t)(n0 + srow) * K + schk * 8;
  const size_t rstep = (size_t)64 * K;

  f32x16 acc[2][NF] = {};

  const int NT = K / 64;                     // 32

#define G8_READ(BUF, KS)                                              \
      bf16x8 af[2], bfv[NF];                                          \
      _Pragma("unroll")                                               \
      for (int m = 0; m < 2; ++m)                                     \
        af[m] = *(const bf16x8*)&As[BUF][(wr * 64 + m * 32 + l31) * 64 \
                                         + ((((KS) * 2 + hi2) ^ rx) * 8)]; \
      _Pragma("unroll")                                               \
      for (int n = 0; n < NF; ++n)                                    \
        bfv[n] = *(const bf16x8*)&Bs[BUF][(wc * (NF * 32) + n * 32 + l31) * 64 \
                                          + ((((KS) * 2 + hi2) ^ rx) * 8)];

#define G8_MMA()                                                      \
      __builtin_amdgcn_s_setprio(1);                                  \
      _Pragma("unroll")                                               \
      for (int m = 0; m < 2; ++m)                                     \
        _Pragma("unroll")                                             \
        for (int n = 0; n < NF; ++n)                                  \
          acc[m][n] = __builtin_amdgcn_mfma_f32_32x32x16_bf16(        \
              af[m], bfv[n], acc[m][n], 0, 0, 0);                     \
      __builtin_amdgcn_s_setprio(0);

// one K-tile in buf U; stages tile tt+1 into buf U^1 during phases 0/1
#define G8_TILE(U, TT)                                                \
  {                                                                   \
    const int tt = (TT);                                              \
    const bool more = (tt < NT - 1);                                  \
    const bf16* a_ = aSrc + (size_t)(tt + 1) * 64;                    \
    const bf16* b_ = bSrc + (size_t)(tt + 1) * 64;                    \
    { /* phase ks0: reads + A staging */                              \
      G8_READ(U, 0)                                                   \
      if (more) {                                                     \
        _Pragma("unroll")                                             \
        for (int j = 0; j < 4; ++j)                                   \
          gload_lds16(a_ + j * rstep, &As[(U) ^ 1][j * 4096 + tid * 8]); \
      }                                                               \
      __builtin_amdgcn_s_barrier();                                   \
      G8_MMA()                                                        \
      __builtin_amdgcn_s_barrier();                                   \
    }                                                                 \
    { /* phase ks1: reads + B staging */                              \
      G8_READ(U, 1)                                                   \
      if (more) {                                                     \
        _Pragma("unroll")                                             \
        for (int j = 0; j < NF; ++j)                                  \
          gload_lds16(b_ + j * rstep, &Bs[(U) ^ 1][j * 4096 + tid * 8]); \
      }                                                               \
      __builtin_amdgcn_s_barrier();                                   \
      G8_MMA()                                                        \
      __builtin_amdgcn_s_barrier();                                   \
    }                                                                 \
    { /* phase ks2 */                                                 \
      G8_READ(U, 2)                                                   \
      __builtin_amdgcn_s_barrier();                                   \
      G8_MMA()                                                        \
      __builtin_amdgcn_s_barrier();                                   \
    }                                                                 \
    { /* phase ks3: last MFMA, then drain next-tile loads + barrier */\
      G8_READ(U, 3)                                                   \
      __builtin_amdgcn_s_barrier();                                   \
      G8_MMA()                                                        \
      asm volatile("s_waitcnt vmcnt(0)" ::: "memory");                \
      __builtin_amdgcn_s_barrier();                                   \
    }                                                                 \
  }

  // prologue: stage tile 0 into buf 0; drain; sync
  {
    #pragma unroll
    for (int j = 0; j < 4; ++j)
      gload_lds16(aSrc + j * rstep, &As[0][j * 4096 + tid * 8]);
    #pragma unroll
    for (int j = 0; j < NF; ++j)
      gload_lds16(bSrc + j * rstep, &Bs[0][j * 4096 + tid * 8]);
    asm volatile("s_waitcnt vmcnt(0)" ::: "memory");
    __builtin_amdgcn_s_barrier();
  }

  for (int t = 0; t < NT; t += 2) {
    G8_TILE(0, t)
    G8_TILE(1, t + 1)
  }

#undef G8_READ
#undef G8_MMA
#undef G8_TILE

  // epilogue: bias + scale + store (32x32 C/D layout, m101-verified)
  const int cb = n0 + wc * (NF * 32) + l31;
  #pragma unroll
  for (int n = 0; n < NF; ++n) {
    const int col = cb + n * 32;
    float bv;
    if (col < sp1)      bv = b0[col];
    else if (col < sp2) bv = b1[col - sp1];
    else                bv = b2[col - sp2];
    const float scl = (col < nscale) ? scale : 1.0f;
    #pragma unroll
    for (int m = 0; m < 2; ++m) {
      const int rb = m0 + wr * 64 + m * 32 + 4 * hi2;
      #pragma unroll
      for (int r = 0; r < 16; ++r) {
        const int row = rb + (r & 3) + 8 * (r >> 2);
        const float v = (acc[m][n][r] + bv) * scl;
        if (OUT_BF16) ((bf16*)Cout)[(size_t)row * N + col] = (bf16)v;
        else          ((float*)Cout)[(size_t)row * N + col] = v;
      }
    }
  }
}

// ---------------- flash attention (EXACT R15 kernel — frozen) ----------------
// 4 waves x 64 q-rows (2 q-sets) = 256 q/block; grid 512 = 2 blocks/CU.
__global__ __launch_bounds__(256, 2) void attn_kernel(
    const bf16* __restrict__ QKV, const bf16* __restrict__ Vtg, bf16* __restrict__ ctx)
{
  __shared__ bf16 smem[4][64 * 64];   // [0..1] K dbuf, [2..3] Vt dbuf; 32 KB

  const int tid = threadIdx.x, lane = tid & 63, wid = tid >> 6;
  const int l31 = lane & 31, hi = lane >> 5;
  const int qt = blockIdx.x & 7;      // 8 q-tiles of 256 rows
  const int bh = blockIdx.x >> 3;
  const int h = bh & 31, b = bh >> 5, kvh = h >> 2;

  const bf16* gK = QKV + (size_t)b * SEQ * QKV_N + 2048 + kvh * 64;
  const bf16* gV = Vtg + (size_t)(b * 8 + kvh) * 64 * SEQ;

  const int sr  = lane >> 3;            // staging row within 8-row group
  const int scn = (lane & 7) ^ sr;      // pre-swizzled logical chunk

  // Q fragments for both q-sets
  bf16x8 qf[4], qf2[4];
  {
    const bf16* qp = QKV + (size_t)(b * SEQ + qt * 256 + wid * 64 + l31) * QKV_N + h * 64 + hi * 8;
    #pragma unroll
    for (int kt = 0; kt < 4; ++kt) qf[kt]  = *(const bf16x8*)(qp + kt * 16);
    const bf16* qp2 = qp + (size_t)32 * QKV_N;
    #pragma unroll
    for (int kt = 0; kt < 4; ++kt) qf2[kt] = *(const bf16x8*)(qp2 + kt * 16);
  }

  bf16x8 onesv;
  #pragma unroll
  for (int j = 0; j < 8; ++j) onesv[j] = (bf16)1.0f;

  f32x16 o0 = {}, o1 = {}, o2 = {}, o3 = {};
  f32x16 lacc = {}, lacc2 = {};

  const int row0 = (wid * 2 + 0) * 8 + sr;
  const int row1 = (wid * 2 + 1) * 8 + sr;
  const bf16* pK0 = gK + (size_t)row0 * QKV_N + scn * 8;
  const bf16* pK1 = gK + (size_t)row1 * QKV_N + scn * 8;
  const bf16* pV0 = gV + (size_t)row0 * SEQ + scn * 8;
  const bf16* pV1 = gV + (size_t)row1 * SEQ + scn * 8;

  gload_lds16(pK0, &smem[0][(wid * 2 + 0) * 512]);
  gload_lds16(pK1, &smem[0][(wid * 2 + 1) * 512]);
  gload_lds16(pV0, &smem[2][(wid * 2 + 0) * 512]);
  gload_lds16(pV1, &smem[2][(wid * 2 + 1) * 512]);
  pK0 += (size_t)64 * QKV_N; pK1 += (size_t)64 * QKV_N; pV0 += 64; pV1 += 64;
  __syncthreads();

  const int rx = l31 & 7;

#define PV_SET(SA, SB, OA, OB, LC)                                        \
    _Pragma("unroll")                                                     \
    for (int s = 0; s < 4; ++s) {                                         \
      const f32x16& sv = (s < 2) ? SA : SB;                               \
      const int rb = (s & 1) * 8;                                         \
      uint32_t Aw = pk2(sv[rb + 0], sv[rb + 1]);                          \
      uint32_t Bw = pk2(sv[rb + 2], sv[rb + 3]);                          \
      uint32_t Cw = pk2(sv[rb + 4], sv[rb + 5]);                          \
      uint32_t Dw = pk2(sv[rb + 6], sv[rb + 7]);                          \
      union { uint32_t w[4]; bf16x8 v; } pf;                              \
      auto rA = __builtin_amdgcn_permlane32_swap(Aw, Cw, false, false);   \
      auto rB = __builtin_amdgcn_permlane32_swap(Bw, Dw, false, false);   \
      pf.w[0] = rA[0]; pf.w[1] = rB[0]; pf.w[2] = rA[1]; pf.w[3] = rB[1]; \
      __builtin_amdgcn_s_setprio(1);                                      \
      OA = __builtin_amdgcn_mfma_f32_32x32x16_bf16(vf[s],     pf.v, OA, 0, 0, 0); \
      OB = __builtin_amdgcn_mfma_f32_32x32x16_bf16(vf[s + 4], pf.v, OB, 0, 0, 0); \
      LC = __builtin_amdgcn_mfma_f32_32x32x16_bf16(onesv,     pf.v, LC, 0, 0, 0); \
      __builtin_amdgcn_s_setprio(0);                                      \
    }

  for (int it = 0; it < 32; ++it) {
    const int cur = it & 1;
    if (it < 31) {
      gload_lds16(pK0, &smem[cur ^ 1][(wid * 2 + 0) * 512]);
      gload_lds16(pK1, &smem[cur ^ 1][(wid * 2 + 1) * 512]);
      gload_lds16(pV0, &smem[2 + (cur ^ 1)][(wid * 2 + 0) * 512]);
      gload_lds16(pV1, &smem[2 + (cur ^ 1)][(wid * 2 + 1) * 512]);
      pK0 += (size_t)64 * QKV_N; pK1 += (size_t)64 * QKV_N; pV0 += 64; pV1 += 64;
    }
    const bf16* Kb = smem[cur];
    const bf16* Vb = smem[2 + cur];

    bf16x8 kf[8];
    #pragma unroll
    for (int kt = 0; kt < 4; ++kt) {
      const int ck = hi + 2 * kt;
      kf[kt]     = *(const bf16x8*)(Kb + (size_t)l31 * 64        + ((ck ^ rx) * 8));
      kf[kt + 4] = *(const bf16x8*)(Kb + (size_t)(32 + l31) * 64 + ((ck ^ rx) * 8));
    }
    f32x16 s0v = {}, s1v = {}, s2v = {}, s3v = {};
    __builtin_amdgcn_s_setprio(1);
    #pragma unroll
    for (int kt = 0; kt < 4; ++kt) {
      s0v = __builtin_amdgcn_mfma_f32_32x32x16_bf16(kf[kt],     qf[kt],  s0v, 0, 0, 0);
      s1v = __builtin_amdgcn_mfma_f32_32x32x16_bf16(kf[kt + 4], qf[kt],  s1v, 0, 0, 0);
      s2v = __builtin_amdgcn_mfma_f32_32x32x16_bf16(kf[kt],     qf2[kt], s2v, 0, 0, 0);
      s3v = __builtin_amdgcn_mfma_f32_32x32x16_bf16(kf[kt + 4], qf2[kt], s3v, 0, 0, 0);
    }
    __builtin_amdgcn_s_setprio(0);

    bf16x8 vf[8];
    #pragma unroll
    for (int s = 0; s < 4; ++s) {
      const int ck = hi + 2 * s;
      vf[s]     = *(const bf16x8*)(Vb + (size_t)l31 * 64        + ((ck ^ rx) * 8));
      vf[s + 4] = *(const bf16x8*)(Vb + (size_t)(32 + l31) * 64 + ((ck ^ rx) * 8));
    }

    #pragma unroll
    for (int r = 0; r < 16; ++r) {
      s0v[r] = EXP2(s0v[r]); s1v[r] = EXP2(s1v[r]);
      s2v[r] = EXP2(s2v[r]); s3v[r] = EXP2(s3v[r]);
    }

    PV_SET(s0v, s1v, o0, o1, lacc)
    PV_SET(s2v, s3v, o2, o3, lacc2)
    __syncthreads();
  }
#undef PV_SET

#define WRITE_SET(OA, OB, LC, QOFF)                                        \
  {                                                                        \
    const float inv = 1.0f / LC[0];                                        \
    OA *= inv; OB *= inv;                                                  \
    uint32_t* ot = (uint32_t*)((bf16*)smem + wid * 2304);                  \
    _Pragma("unroll")                                                      \
    for (int r = 0; r < 16; r += 2) {                                      \
      const int d = (r & 3) + 8 * (r >> 2) + 4 * hi;                       \
      ot[l31 * 36 + (d >> 1)]        = pk2(OA[r], OA[r + 1]);              \
      ot[l31 * 36 + ((32 + d) >> 1)] = pk2(OB[r], OB[r + 1]);              \
    }                                                                      \
    __syncthreads();                                                       \
    {                                                                      \
      const int q2 = lane >> 1, hf = lane & 1;                             \
      const bf16* src = (const bf16*)smem + wid * 2304 + q2 * 72 + hf * 32;\
      bf16* dst = ctx + (size_t)(b * SEQ + qt * 256 + wid * 64 + (QOFF) + q2) * D_MODEL \
                      + h * 64 + hf * 32;                                  \
      _Pragma("unroll")                                                    \
      for (int k = 0; k < 4; ++k)                                          \
        *(bf16x8*)(dst + k * 8) = *(const bf16x8*)(src + k * 8);           \
    }                                                                      \
    __syncthreads();                                                       \
  }

  WRITE_SET(o0, o1, lacc, 0)
  WRITE_SET(o2, o3, lacc2, 32)
#undef WRITE_SET
}

// ---------------------------------------------------------------------------
extern "C" void kernel_launch(void* const* d_in, const int* in_sizes, int n_in,
                              void* d_out, int out_size, void* d_ws, size_t ws_size,
                              hipStream_t stream) {
  const float* x  = (const float*)d_in[0];
  const float* Wq = (const float*)d_in[1];
  const float* bq = (const float*)d_in[2];
  const float* Wk = (const float*)d_in[3];
  const float* bk = (const float*)d_in[4];
  const float* Wv = (const float*)d_in[5];
  const float* bv = (const float*)d_in[6];
  const float* Wo = (const float*)d_in[7];
  const float* bo = (const float*)d_in[8];
  float* out = (float*)d_out;

  char* ws = (char*)d_ws;
  size_t off = 0;
  bf16* xb   = (bf16*)(ws + off); off += (size_t)MTOT * D_MODEL * 2;       // x bf16
  bf16* Wall = (bf16*)(ws + off); off += (size_t)QKV_N * D_MODEL * 2;      // [Wq^T;Wk^T;Wv^T]
  bf16* Wot  = (bf16*)(ws + off); off += (size_t)D_MODEL * D_MODEL * 2;    // Wo^T
  bf16* QKV  = (bf16*)(ws + off); off += (size_t)MTOT * QKV_N * 2;         // [Q|K|V]
  bf16* ctx  = (bf16*)(ws + off); off += (size_t)MTOT * D_MODEL * 2;       // attn out
  bf16* Vtg  = (bf16*)(ws + off); off += (size_t)16 * 64 * SEQ * 2;        // V^T

  // 1) x -> bf16
  {
    int n = MTOT * D_MODEL;
    cvt_f32_bf16<<<n / 4 / 256, 256, 0, stream>>>(x, xb, n);
  }
  // 2) all weight transposes, one launch
  transpose_all<<<dim3(32, 32, 4), 256, 0, stream>>>(Wq, Wk, Wv, Wo, Wall, Wot);

  // 3) fused QKV projection: BM=256 x BN=192 -> 16x16 = 256 blocks (full fill)
  gemm256<3, 1><<<dim3(16, 16), 512, 0, stream>>>(
      xb, Wall, bq, bk, bv, 2048, 2560, 2048, QSCALE, QKV, QKV_N, D_MODEL);

  // 3b) V -> V^T
  transpose_v<<<dim3(SEQ / 64, 16), 256, 0, stream>>>(QKV, Vtg);

  // 4) attention: 512 blocks (256 q-rows each), 2 blocks/CU
  attn_kernel<<<dim3((SEQ / 256) * BATCH * 32), 256, 0, stream>>>(QKV, Vtg, ctx);

  // 5) output projection: BM=256 x BN=128 -> 16x16 = 256 blocks (full fill)
  gemm256<2, 0><<<dim3(16, 16), 512, 0, stream>>>(
      ctx, Wot, bo, bo, bo, 2048, 2048, 0, 1.0f, out, D_MODEL, D_MODEL);
}